// Round 10
// baseline (1449.956 us; speedup 1.0000x reference)
//
#include <hip/hip_runtime.h>
#include <hip/hip_bf16.h>

typedef unsigned int u32;
typedef unsigned short ushort;
typedef __attribute__((ext_vector_type(8))) short short8;
typedef __attribute__((ext_vector_type(8))) ushort ushort8;
typedef __attribute__((ext_vector_type(4))) float f32x4;

#define NN 50000
#define NPAD 50048       // padded to 64-row multiple for MFMA blocks
#define EE 800000
#define GG 64
#define HH 3
#define CC 64
#define IN_DIM 75
#define KP1 96           // padded K for layer-1 GEMM
#define HC 192           // H*C
#define XS 256           // padded row stride (bf16) of gather source
#define TOTAL (EE + NN)  // edge entries incl self loops

// ---------------- helpers ----------------
__device__ __forceinline__ u32 fmap(float f) {
    u32 u = __float_as_uint(f);
    return (u & 0x80000000u) ? ~u : (u | 0x80000000u);
}
__device__ __forceinline__ float funmap(u32 m) {
    u32 u = (m & 0x80000000u) ? (m ^ 0x80000000u) : ~m;
    return __uint_as_float(u);
}
__device__ __forceinline__ float bf2f(ushort u) {
    return __uint_as_float(((u32)u) << 16);
}

// ---------------- degree + edge-attr sum ----------------
__global__ void k_deg(const int* __restrict__ ei, const float* __restrict__ eattr,
                      int* __restrict__ deg, float* __restrict__ attrsum) {
    int e = blockIdx.x * 256 + threadIdx.x;
    if (e >= EE) return;
    int d = ei[EE + e];
    atomicAdd(&deg[d], 1);
    atomicAdd(&attrsum[d], eattr[e]);
}

// ---------------- prefix scan (deg+1) : 2-level ----------------
__global__ void k_scan1(const int* __restrict__ deg, u32* __restrict__ startv,
                        u32* __restrict__ blocksum) {
    __shared__ u32 sh[1024];
    int t = threadIdx.x;
    int n = blockIdx.x * 1024 + t;
    u32 v = (n < NN) ? (u32)(deg[n] + 1) : 0u;
    u32 val = v;
    sh[t] = val;
    __syncthreads();
    for (int off = 1; off < 1024; off <<= 1) {
        u32 y = (t >= off) ? sh[t - off] : 0u;
        __syncthreads();
        val += y;
        sh[t] = val;
        __syncthreads();
    }
    if (n < NN) startv[n] = val - v;   // block-exclusive
    if (t == 0) blocksum[blockIdx.x] = sh[1023];
}

__global__ void k_scan2(u32* __restrict__ blocksum, int nb) {
    if (threadIdx.x == 0) {
        u32 acc = 0;
        for (int b = 0; b < nb; b++) { u32 t = blocksum[b]; blocksum[b] = acc; acc += t; }
    }
}

__global__ void k_scan3(u32* __restrict__ startv, const u32* __restrict__ blocksum,
                        u32* __restrict__ cursor) {
    int n = blockIdx.x * 256 + threadIdx.x;
    if (n >= NN) return;
    u32 s = startv[n] + blocksum[n >> 10];
    startv[n] = s;
    cursor[n] = s;
}

// per-graph node counts via binary search on SORTED batch (no atomics).
__global__ void k_gcnt(const int* __restrict__ batch, int* __restrict__ pcnt) {
    int g = threadIdx.x;   // 0..63
    if (g >= GG) return;
    int lo0 = 0, hi0 = NN;        // lower_bound(g)
    while (lo0 < hi0) { int mid = (lo0 + hi0) >> 1; if (batch[mid] < g) lo0 = mid + 1; else hi0 = mid; }
    int lo1 = lo0, hi1 = NN;      // lower_bound(g+1)
    while (lo1 < hi1) { int mid = (lo1 + hi1) >> 1; if (batch[mid] < g + 1) lo1 = mid + 1; else hi1 = mid; }
    pcnt[g] = lo1 - lo0;
}

// fill CSR-ordered streams: srcP/eaP/dstP packed by destination segment; iOf maps pos->entry
__global__ void k_fill(const int* __restrict__ ei, const float* __restrict__ eattr,
                       const float* __restrict__ attrsum, const int* __restrict__ deg,
                       u32* __restrict__ cursor, int* __restrict__ srcP,
                       int* __restrict__ dstP, float* __restrict__ eaP,
                       u32* __restrict__ iOf) {
    int i = blockIdx.x * 256 + threadIdx.x;
    if (i >= TOTAL) return;
    int s, d;
    float ea;
    if (i < EE) {
        s = ei[i]; d = ei[EE + i]; ea = eattr[i];
    } else {
        s = d = i - EE;
        ea = attrsum[s] / fmaxf((float)deg[s], 1.f);
    }
    u32 pos = atomicAdd(&cursor[d], 1u);
    srcP[pos] = s;
    dstP[pos] = d;
    eaP[pos] = ea;
    iOf[pos] = (u32)i;
}

// ---------------- prep: Wt conversions + pmax init + wedot ----------------
__global__ void k_prep(const float* __restrict__ W1, const float* __restrict__ W2,
                       const float* __restrict__ We1, const float* __restrict__ ae1,
                       const float* __restrict__ We2, const float* __restrict__ ae2,
                       __hip_bfloat16* __restrict__ Wt1, __hip_bfloat16* __restrict__ Wt2,
                       u32* __restrict__ pmax, float* __restrict__ wedot) {
    int i = blockIdx.x * 256 + threadIdx.x;
    if (i < HC * KP1) {
        int j = i / KP1, k = i - j * KP1;
        Wt1[i] = __float2bfloat16(k < IN_DIM ? W1[k * HC + j] : 0.f);
    }
    if (i < HC * HC) {
        int j = i / HC, k = i - j * HC;
        Wt2[i] = __float2bfloat16(W2[k * HC + j]);
    }
    if (i < GG * HC) pmax[i] = 0x007FFFFFu;   // fmap(-inf)
    if (blockIdx.x == 0) {
        int w = threadIdx.x >> 6, c = threadIdx.x & 63;
        for (int dd = w; dd < 6; dd += 4) {
            int layer = dd / 3, h = dd - 3 * layer;
            const float* We = layer ? We2 : We1;
            const float* ae = layer ? ae2 : ae1;
            float v = We[h * 64 + c] * ae[h * 64 + c];
#pragma unroll
            for (int off = 32; off; off >>= 1) v += __shfl_xor(v, off, 64);
            if (c == 0) wedot[dd] = v;
        }
    }
}

// xb[NPAD][KP1] bf16, zero-padded rows and k>=IN_DIM
__global__ void k_xconv(const float* __restrict__ x, __hip_bfloat16* __restrict__ xb) {
    int i = blockIdx.x * 256 + threadIdx.x;
    if (i >= NPAD * KP1) return;
    int n = i / KP1, k = i - n * KP1;
    float v = (n < NN && k < IN_DIM) ? x[n * IN_DIM + k] : 0.f;
    xb[i] = __float2bfloat16(v);
}

// ---------------- MFMA GEMM + fused attdot epilogue, bf16 output (stride OS) ----------
// outb[NPAD][OS](bf16) = A[NPAD,KPAD] @ Wt^T (cols 0..191; cols 192..OS-1 zeroed).
// A row-major bf16 [NPAD][KPAD]; Wt row-major bf16 [192][KPAD] (Wt[j][k]=W[k][j]).
// Block: 256 thr = 4 waves; 64 rows x 192 cols per block; 12 col-frags per wave.
template <int KPAD, int OS>
__global__ __launch_bounds__(256) void k_mfma_gemm(const __hip_bfloat16* __restrict__ A,
                                                   const __hip_bfloat16* __restrict__ Wt,
                                                   const float* __restrict__ asrcw,
                                                   const float* __restrict__ adstw,
                                                   __hip_bfloat16* __restrict__ outb,
                                                   float* __restrict__ asrc,
                                                   float* __restrict__ adst) {
    int wid = threadIdx.x >> 6;
    int lane = threadIdx.x & 63;
    int r0 = blockIdx.x * 64 + wid * 16;
    int lr = lane & 15;     // A: row-in-16, B: col-in-16
    int g = lane >> 4;      // k-subgroup (8 elems each)
    const short* Ab = (const short*)A;
    const short* Wb = (const short*)Wt;
    f32x4 acc[12];
#pragma unroll
    for (int f = 0; f < 12; f++) acc[f] = (f32x4){0.f, 0.f, 0.f, 0.f};
#pragma unroll
    for (int k0 = 0; k0 < KPAD; k0 += 32) {
        short8 a = *(const short8*)(Ab + (size_t)(r0 + lr) * KPAD + k0 + 8 * g);
#pragma unroll
        for (int f = 0; f < 12; f++) {
            short8 b = *(const short8*)(Wb + (size_t)(f * 16 + lr) * KPAD + k0 + 8 * g);
            acc[f] = __builtin_amdgcn_mfma_f32_16x16x32_bf16(a, b, acc[f], 0, 0, 0);
        }
    }
    int rbase = r0 + 4 * g;   // D: col = lane&15, row = 4*(lane>>4)+reg
#pragma unroll
    for (int f = 0; f < 12; f++) {
        int col = f * 16 + lr;
#pragma unroll
        for (int r = 0; r < 4; r++) {
            int row = rbase + r;
            if (row < NN) outb[(size_t)row * OS + col] = __float2bfloat16(acc[f][r]);
        }
    }
    // zero the pad columns (gather source must read zeros there)
    if (OS > HC) {
        u32* ob = (u32*)outb;
        int row0 = blockIdx.x * 64;
        const int padw = (OS - HC) >> 1;   // u32 words per row
        for (int idx = threadIdx.x; idx < 64 * padw; idx += 256) {
            int row = idx / padw, cc = idx - row * padw;
            ob[(size_t)(row0 + row) * (OS >> 1) + (HC >> 1) + cc] = 0u;
        }
    }
    // fused attdot: per row, per head, weighted col-sum reduced across 16-lane group
    float asw[12], adw[12];
#pragma unroll
    for (int f = 0; f < 12; f++) {
        asw[f] = asrcw[f * 16 + lr];
        adw[f] = adstw[f * 16 + lr];
    }
#pragma unroll
    for (int h = 0; h < 3; h++) {
#pragma unroll
        for (int r = 0; r < 4; r++) {
            float p = acc[4 * h][r] * asw[4 * h] + acc[4 * h + 1][r] * asw[4 * h + 1] +
                      acc[4 * h + 2][r] * asw[4 * h + 2] + acc[4 * h + 3][r] * asw[4 * h + 3];
            float q = acc[4 * h][r] * adw[4 * h] + acc[4 * h + 1][r] * adw[4 * h + 1] +
                      acc[4 * h + 2][r] * adw[4 * h + 2] + acc[4 * h + 3][r] * adw[4 * h + 3];
#pragma unroll
            for (int off = 1; off < 16; off <<= 1) {
                p += __shfl_xor(p, off, 64);
                q += __shfl_xor(q, off, 64);
            }
            int row = rbase + r;
            if (lr == 0 && row < NN) {
                asrc[row * 3 + h] = p;
                adst[row * 3 + h] = q;
            }
        }
    }
}

// ---------------- e = exp(leakyrelu(alpha)) in PACKED order, streaming (high TLP) ------
__global__ void k_alphaP(const int* __restrict__ srcP, const int* __restrict__ dstP,
                         const float* __restrict__ eaP, const float* __restrict__ asrc,
                         const float* __restrict__ adst, const float* __restrict__ wedot,
                         int woff, float* __restrict__ eP) {
    int p = blockIdx.x * 256 + threadIdx.x;
    if (p >= TOTAL) return;
    int s = srcP[p], d = dstP[p];
    float ea = eaP[p];
#pragma unroll
    for (int h = 0; h < 3; h++) {
        float a = asrc[s * 3 + h] + adst[d * 3 + h] + ea * wedot[woff + h];
        a = (a > 0.f) ? a : 0.2f * a;
        eP[(size_t)p * 3 + h] = __expf(a);
    }
}

// ---------------- wide gather: 1 wave/node, 2 edges per 1KB load instruction ----------
// xhb2[NPAD][XS] bf16 (cols>=192 zero). Lane = half*32+lc; lane owns cols lc*8..+7 of
// the half's edge row (16B ushort8 load). Halves combined via shfl_xor(32).
template <int LAYER2>
__global__ __launch_bounds__(256) void k_gatherSM(const u32* __restrict__ startv,
                           const int* __restrict__ deg, const int* __restrict__ srcP,
                           const float* __restrict__ eP,
                           const __hip_bfloat16* __restrict__ xhb2,
                           const float* __restrict__ bias, float* __restrict__ rdenom,
                           __hip_bfloat16* __restrict__ hb, const int* __restrict__ batch,
                           float* __restrict__ psum, u32* __restrict__ pmax) {
    int w = threadIdx.x >> 6;
    int n = blockIdx.x * 4 + w;
    if (n >= NN) return;
    int lane = threadIdx.x & 63;
    int half = lane >> 5;
    int lc = lane & 31;
    int myh = lc >> 3; if (myh > 2) myh = 2;     // pad lanes reuse head2's e (acc is 0 anyway)
    u32 st = startv[n];
    int L = deg[n] + 1;
    const int* sp = srcP + st;
    const float* epn = eP + (size_t)st * 3;
    const ushort* xb = (const ushort*)xhb2;

    float a0=0.f,a1=0.f,a2=0.f,a3=0.f,a4=0.f,a5=0.f,a6=0.f,a7=0.f,ssum=0.f;

#define GSTEP(qv) { int s_ = sp[qv]; float e_ = epn[(size_t)(qv) * 3 + myh];            \
        ushort8 v_ = *(const ushort8*)(xb + (size_t)s_ * XS + lc * 8);                  \
        a0 += e_ * bf2f(v_[0]); a1 += e_ * bf2f(v_[1]);                                 \
        a2 += e_ * bf2f(v_[2]); a3 += e_ * bf2f(v_[3]);                                 \
        a4 += e_ * bf2f(v_[4]); a5 += e_ * bf2f(v_[5]);                                 \
        a6 += e_ * bf2f(v_[6]); a7 += e_ * bf2f(v_[7]); ssum += e_; }

    int p = 0;
    for (; p + 8 <= L; p += 8) {        // 4 independent 1KB loads in flight (8 edges)
        GSTEP(p + half)
        GSTEP(p + 2 + half)
        GSTEP(p + 4 + half)
        GSTEP(p + 6 + half)
    }
    for (; p < L; p += 2) {             // guarded tail, 2 edges/step
        int q = p + half;
        bool act = q < L;
        int s_ = act ? sp[q] : 0;
        float e_ = act ? epn[(size_t)q * 3 + myh] : 0.f;
        ushort8 v_ = *(const ushort8*)(xb + (size_t)s_ * XS + lc * 8);
        a0 += e_ * bf2f(v_[0]); a1 += e_ * bf2f(v_[1]);
        a2 += e_ * bf2f(v_[2]); a3 += e_ * bf2f(v_[3]);
        a4 += e_ * bf2f(v_[4]); a5 += e_ * bf2f(v_[5]);
        a6 += e_ * bf2f(v_[6]); a7 += e_ * bf2f(v_[7]); ssum += e_;
    }
#undef GSTEP

    a0 += __shfl_xor(a0, 32, 64); a1 += __shfl_xor(a1, 32, 64);
    a2 += __shfl_xor(a2, 32, 64); a3 += __shfl_xor(a3, 32, 64);
    a4 += __shfl_xor(a4, 32, 64); a5 += __shfl_xor(a5, 32, 64);
    a6 += __shfl_xor(a6, 32, 64); a7 += __shfl_xor(a7, 32, 64);
    ssum += __shfl_xor(ssum, 32, 64);

    float r = 1.f / (ssum + 1e-16f);
    if (half == 0 && lc < 24) {
        if ((lc & 7) == 0) rdenom[n * 3 + myh] = r;
        const f32x4* bp = (const f32x4*)(bias + lc * 8);
        f32x4 b0 = bp[0], b1 = bp[1];
        float o[8] = {a0 * r + b0[0], a1 * r + b0[1], a2 * r + b0[2], a3 * r + b0[3],
                      a4 * r + b1[0], a5 * r + b1[1], a6 * r + b1[2], a7 * r + b1[3]};
#pragma unroll
        for (int k = 0; k < 8; k++) o[k] = (o[k] > 0.f) ? o[k] : expm1f(o[k]);
        if (LAYER2) {
            int gi = batch[n];
#pragma unroll
            for (int k = 0; k < 8; k++) {
                atomicAdd(&psum[gi * HC + lc * 8 + k], o[k]);
                atomicMax(&pmax[gi * HC + lc * 8 + k], fmap(o[k]));
            }
        } else {
            short8 hv;
#pragma unroll
            for (int k = 0; k < 8; k++)
                hv[k] = (short)__bfloat16_as_ushort(__float2bfloat16(o[k]));
            *(short8*)((short*)hb + (size_t)n * HC + lc * 8) = hv;
        }
    }
}

// ---------------- normalized attn, scatter-write in original entry order ----------------
__global__ void k_attnout(const u32* __restrict__ iOf, const int* __restrict__ dstP,
                          const float* __restrict__ eP, const float* __restrict__ rdenom,
                          float* __restrict__ attn) {
    int pos = blockIdx.x * 256 + threadIdx.x;
    if (pos >= TOTAL) return;
    int d = dstP[pos];
    u32 i = iOf[pos];
    float e0 = eP[(size_t)pos * 3 + 0];
    float e1 = eP[(size_t)pos * 3 + 1];
    float e2 = eP[(size_t)pos * 3 + 2];
    attn[(size_t)i * 3 + 0] = e0 * rdenom[d * 3 + 0];
    attn[(size_t)i * 3 + 1] = e1 * rdenom[d * 3 + 1];
    attn[(size_t)i * 3 + 2] = e2 * rdenom[d * 3 + 2];
}

// ---------------- head MLP ----------------
__global__ void k_head(const float* __restrict__ psum, const u32* __restrict__ pmax,
                       const int* __restrict__ pcnt, const float* __restrict__ fc1w,
                       const float* __restrict__ fc1b, const float* __restrict__ fc2w,
                       const float* __restrict__ fc2b, float* __restrict__ logits) {
    __shared__ float z[2 * HC];
    int g = blockIdx.x;
    int t = threadIdx.x;   // 0..63
    float cnt = fmaxf((float)pcnt[g], 1.f);
    for (int k = t; k < 2 * HC; k += 64)
        z[k] = (k < HC) ? psum[g * HC + k] / cnt : funmap(pmax[g * HC + (k - HC)]);
    __syncthreads();
    float acc = fc1b[t];
    for (int k = 0; k < 2 * HC; k++) acc += z[k] * fc1w[k * 64 + t];
    acc = fmaxf(acc, 0.f);
    float v = acc * fc2w[t];
#pragma unroll
    for (int off = 32; off; off >>= 1) v += __shfl_xor(v, off, 64);
    if (t == 0) logits[g] = v + fc2b[0];
}

// ---------------- launcher ----------------
extern "C" void kernel_launch(void* const* d_in, const int* in_sizes, int n_in,
                              void* d_out, int out_size, void* d_ws, size_t ws_size,
                              hipStream_t stream) {
    const float* x     = (const float*)d_in[0];
    const float* eattr = (const float*)d_in[1];
    const float* W1    = (const float*)d_in[2];
    const float* as1   = (const float*)d_in[3];
    const float* ad1   = (const float*)d_in[4];
    const float* We1   = (const float*)d_in[5];
    const float* ae1   = (const float*)d_in[6];
    const float* b1    = (const float*)d_in[7];
    const float* W2    = (const float*)d_in[8];
    const float* as2   = (const float*)d_in[9];
    const float* ad2   = (const float*)d_in[10];
    const float* We2   = (const float*)d_in[11];
    const float* ae2   = (const float*)d_in[12];
    const float* b2    = (const float*)d_in[13];
    const float* fc1w  = (const float*)d_in[14];
    const float* fc1b  = (const float*)d_in[15];
    const float* fc2w  = (const float*)d_in[16];
    const float* fc2b  = (const float*)d_in[17];
    const int* ei      = (const int*)d_in[18];
    const int* batch   = (const int*)d_in[19];

    float* logits = (float*)d_out;
    float* attn1  = logits + GG;
    float* attn2  = attn1 + (size_t)TOTAL * 3;

    // workspace layout
    float* eP      = (float*)d_ws;                   // TOTAL*3 (unnormalized e, packed)
    int*   srcP    = (int*)(eP + (size_t)TOTAL * 3);
    int*   dstP    = srcP + TOTAL;
    float* eaP     = (float*)(dstP + TOTAL);
    u32*   iOf     = (u32*)(eaP + TOTAL);
    int*   deg     = (int*)(iOf + TOTAL);
    float* attrsum = (float*)(deg + NN);
    float* asrc    = attrsum + NN;                   // N*3
    float* adst    = asrc + NN * 3;                  // N*3
    float* rdenom  = adst + NN * 3;                  // N*3
    u32*   startv  = (u32*)(rdenom + NN * 3);        // N
    u32*   cursor  = startv + NN;                    // N
    u32*   blocksum= cursor + NN;                    // 64
    float* wedot   = (float*)(blocksum + 64);        // 8
    float* psum    = wedot + 8;                      // G*192
    u32*   pmax    = (u32*)(psum + GG * HC);         // G*192
    int*   pcnt    = (int*)(pmax + GG * HC);         // G
    __hip_bfloat16* xb   = (__hip_bfloat16*)(pcnt + 64);       // NPAD*KP1  (layer-1 GEMM in)
    __hip_bfloat16* xhb2 = xb + (size_t)NPAD * KP1;            // NPAD*XS   (GEMM out, padded gather src)
    __hip_bfloat16* hb   = xhb2 + (size_t)NPAD * XS;           // NPAD*192  (layer-1 h, GEMM2 in)
    __hip_bfloat16* Wt1  = hb + (size_t)NPAD * HC;             // 192*KP1
    __hip_bfloat16* Wt2  = Wt1 + (size_t)HC * KP1;             // 192*192

    // zero init
    hipMemsetAsync(deg, 0, NN * sizeof(int), stream);
    hipMemsetAsync(attrsum, 0, NN * sizeof(float), stream);
    hipMemsetAsync(psum, 0, GG * HC * sizeof(float), stream);
    hipMemsetAsync(hb + (size_t)NN * HC, 0, (size_t)(NPAD - NN) * HC * sizeof(__hip_bfloat16), stream);

    // graph structure (shared by both layers) + weight prep
    k_deg<<<(EE + 255) / 256, 256, 0, stream>>>(ei, eattr, deg, attrsum);
    k_scan1<<<49, 1024, 0, stream>>>(deg, startv, blocksum);
    k_scan2<<<1, 64, 0, stream>>>(blocksum, 49);
    k_scan3<<<(NN + 255) / 256, 256, 0, stream>>>(startv, blocksum, cursor);
    k_gcnt<<<1, 64, 0, stream>>>(batch, pcnt);
    k_fill<<<(TOTAL + 255) / 256, 256, 0, stream>>>(ei, eattr, attrsum, deg, cursor,
                                                    srcP, dstP, eaP, iOf);
    k_prep<<<(HC * HC + 255) / 256, 256, 0, stream>>>(W1, W2, We1, ae1, We2, ae2,
                                                      Wt1, Wt2, pmax, wedot);
    k_xconv<<<(NPAD * KP1 + 255) / 256, 256, 0, stream>>>(x, xb);

    const int GB = NPAD / 64;       // 782 MFMA blocks
    const int GGB = (NN + 3) / 4;   // gather blocks (4 nodes each)

    // ---- layer 1 ----
    k_mfma_gemm<KP1, XS><<<GB, 256, 0, stream>>>(xb, Wt1, as1, ad1, xhb2, asrc, adst);
    k_alphaP<<<(TOTAL + 255) / 256, 256, 0, stream>>>(srcP, dstP, eaP, asrc, adst,
                                                      wedot, 0, eP);
    k_gatherSM<0><<<GGB, 256, 0, stream>>>(startv, deg, srcP, eP, xhb2, b1, rdenom,
                                           hb, batch, psum, pmax);
    k_attnout<<<(TOTAL + 255) / 256, 256, 0, stream>>>(iOf, dstP, eP, rdenom, attn1);

    // ---- layer 2 ----
    k_mfma_gemm<HC, XS><<<GB, 256, 0, stream>>>(hb, Wt2, as2, ad2, xhb2, asrc, adst);
    k_alphaP<<<(TOTAL + 255) / 256, 256, 0, stream>>>(srcP, dstP, eaP, asrc, adst,
                                                      wedot, 3, eP);
    k_gatherSM<1><<<GGB, 256, 0, stream>>>(startv, deg, srcP, eP, xhb2, b2, rdenom,
                                           hb, batch, psum, pmax);
    k_attnout<<<(TOTAL + 255) / 256, 256, 0, stream>>>(iOf, dstP, eP, rdenom, attn2);

    // ---- head ----
    k_head<<<GG, 64, 0, stream>>>(psum, pmax, pcnt, fc1w, fc1b, fc2w, fc2b, logits);
}